// Round 20
// baseline (104.948 us; speedup 1.0000x reference)
//
#include <hip/hip_runtime.h>

#define EMB 16
#define NPB 98                // right-nodes per bucket (NB ~ 1021 -> 4 blocks/CU)
#define NHIST 128             // padded per-node hist (rl < NPB < 128)
#define MAXNB 1024
#define PCHUNK 6656           // edges per chunk-sort block (13 * 512)
#define RPTC 13               // PCHUNK / 512
#define MAXCHUNKS 512
#define REC_CAP 2048          // records per gather LDS tile
#define RPT 4                 // REC_CAP / 512
typedef unsigned int u32;
typedef unsigned long long u64;

__global__ void zero_f32(float* __restrict__ p, size_t n) {
    size_t i = (size_t)blockIdx.x * blockDim.x + threadIdx.x;
    size_t stride = (size_t)gridDim.x * blockDim.x;
    for (; i < n; i += stride) p[i] = 0.0f;
}

__global__ void zero_i32(int* __restrict__ p, int n) {
    int i = blockIdx.x * blockDim.x + threadIdx.x;
    if (i < n) p[i] = 0;
}

__device__ __forceinline__ u32 bf16bits_rne(float x) {
    u32 u = __float_as_uint(x);
    return (u + 0x7fffu + ((u >> 16) & 1u)) >> 16;
}

// Packed bf16 linear: Y[row*8+h] = pack(bf16(row@W[:,h+8]+b), bf16(row@W[:,h]+b))
__global__ void linear16_pack_kernel(const float* __restrict__ X, const float* __restrict__ W,
                                     const float* __restrict__ b, u32* __restrict__ Y, int N) {
    int tid = blockIdx.x * blockDim.x + threadIdx.x;
    int row = tid >> 3;
    int h = tid & 7;
    if (row >= N) return;
    float a0 = b ? b[h] : 0.0f;
    float a1 = b ? b[h + 8] : 0.0f;
    const float* xr = X + (size_t)row * EMB;
#pragma unroll
    for (int k = 0; k < EMB; ++k) {
        float xv = xr[k];
        a0 = fmaf(xv, W[k * EMB + h], a0);
        a1 = fmaf(xv, W[k * EMB + h + 8], a1);
    }
    Y[(size_t)row * 8 + h] = (bf16bits_rne(a1) << 16) | bf16bits_rne(a0);
}

// Plain f32 linear (fallback path)
__global__ void linear16_kernel(const float* __restrict__ X, const float* __restrict__ W,
                                const float* __restrict__ b, float* __restrict__ Y, int N) {
    int tid = blockIdx.x * blockDim.x + threadIdx.x;
    int row = tid >> 4;
    int j = tid & 15;
    if (row >= N) return;
    float acc = b ? b[j] : 0.0f;
    const float* xr = X + (size_t)row * EMB;
#pragma unroll
    for (int k = 0; k < EMB; ++k) acc = fmaf(xr[k], W[k * EMB + j], acc);
    Y[(size_t)row * EMB + j] = acc;
}

// ---------------- chunk-sort: single read pass; bucket-major int2 cnt/base ----
// Record: [f:32][l:24][rl:8]; cbM[b*nchunks+c] = {cnt, cbase}
__launch_bounds__(512)
__global__ void chunk_sort_kernel(const int* __restrict__ eidx, const float* __restrict__ ef,
                                  u64* __restrict__ rec, int2* __restrict__ cbM,
                                  int E, int NB, int nchunks) {
    __shared__ u64 srec[PCHUNK];   // 52 KB
    __shared__ int hist[MAXNB];    // 4 KB counts -> bases
    __shared__ int wsum[8];
    int t = threadIdx.x;
    int lane = t & 63, wid = t >> 6;
    int c = blockIdx.x;
    long long base = (long long)c * PCHUNK;
    int n = (int)(((long long)E - base) < PCHUNK ? ((long long)E - base) : PCHUNK);
    const int* ridx = eidx + E;

    for (int i = t; i < NB; i += 512) hist[i] = 0;
    __syncthreads();
    // single load pass: record + (bucket,rank) in registers
    u64 rcv[RPTC];
    int pk[RPTC];   // (bb << 13) | rank
#pragma unroll
    for (int k = 0; k < RPTC; ++k) {
        int i = t + k * 512;
        rcv[k] = 0; pk[k] = 0;
        if (i < n) {
            int r = ridx[base + i];
            int l = eidx[base + i];
            float f = ef[base + i];
            int bb = r / NPB;
            int rl = r - bb * NPB;
            int rank = atomicAdd(&hist[bb], 1);
            rcv[k] = ((u64)__float_as_uint(f) << 32) | ((u64)(u32)l << 8) | (u32)rl;
            pk[k] = (bb << 13) | rank;
        }
    }
    __syncthreads();
    // hierarchical wave scan over NB counts, 2 per thread (1 barrier)
    int b0 = 2 * t, b1 = 2 * t + 1;
    int v0 = (b0 < NB) ? hist[b0] : 0;
    int v1 = (b1 < NB) ? hist[b1] : 0;
    int s2 = v0 + v1;
    int inc = s2;
#pragma unroll
    for (int d = 1; d < 64; d <<= 1) {
        int x = __shfl_up(inc, d, 64);
        if (lane >= d) inc += x;
    }
    if (lane == 63) wsum[wid] = inc;
    __syncthreads();
    int off = 0;
#pragma unroll
    for (int w = 0; w < 8; ++w) off += (w < wid) ? wsum[w] : 0;
    int ex = off + inc - s2;
    if (b0 < NB) { cbM[(size_t)b0 * nchunks + c] = make_int2(v0, ex);      hist[b0] = ex; }
    if (b1 < NB) { cbM[(size_t)b1 * nchunks + c] = make_int2(v1, ex + v0); hist[b1] = ex + v0; }
    __syncthreads();
    // scatter: position = base + rank, plain LDS write
#pragma unroll
    for (int k = 0; k < RPTC; ++k) {
        int i = t + k * 512;
        if (i < n) srec[hist[pk[k] >> 13] + (pk[k] & 8191)] = rcv[k];
    }
    __syncthreads();
    for (int i = t; i < n; i += 512) rec[base + i] = srec[i];
}

// ---------------- gather + fused per-node epilogue ----------------
// One block per 98-node bucket; 4 owner threads/node; contiguous int2 run-table
// read; addr-translation table; zero fp atomics; MLP epilogue in-block.
__launch_bounds__(512)
__global__ void bucket_gather_kernel(const u64* __restrict__ rec, const int2* __restrict__ cbM,
                                     const u32* __restrict__ Lpk, const u32* __restrict__ Rpk,
                                     const float* __restrict__ We, const float* __restrict__ rf,
                                     const float* __restrict__ Wf, const float* __restrict__ bf,
                                     const float* __restrict__ Wp, const float* __restrict__ bp,
                                     const float* __restrict__ Wo1, const float* __restrict__ bo1,
                                     const float* __restrict__ Wo2, const float* __restrict__ bo2,
                                     float* __restrict__ out,
                                     int n_right, int NB, int nchunks) {
    __shared__ u64 srec[REC_CAP];                 // 16 KB
    __shared__ u32 addrtab[REC_CAP];              // 8 KB
    __shared__ int runsum[MAXCHUNKS + 1];         // 2 KB
    __shared__ int rbase[MAXCHUNKS];              // 2 KB
    __shared__ int hist[NHIST], base_[NHIST];     // 1 KB
    __shared__ int wsum[8];
    __shared__ float sWf[256], sWp[256], sWo1[512], sWo2[256], sb[64];  // 5.3 KB
    int b = blockIdx.x;
    int t = threadIdx.x;
    int lane = t & 63, wid = t >> 6;
    int node0 = b * NPB;

    // stage epilogue weights (covered by the scan's barrier)
    if (t < 256) { sWf[t] = Wf[t]; sWp[t] = Wp[t]; sWo2[t] = Wo2[t]; }
    sWo1[t] = Wo1[t];
    if (t < 16) { sb[t] = bf[t]; sb[16 + t] = bp[t]; sb[32 + t] = bo1[t]; sb[48 + t] = bo2[t]; }

    // contiguous run-table read + hierarchical wave scan (1 barrier)
    int len = 0, cb = 0;
    if (t < nchunks) { int2 v = cbM[(size_t)b * nchunks + t]; len = v.x; cb = v.y; }
    int inc = len;
#pragma unroll
    for (int d = 1; d < 64; d <<= 1) {
        int x = __shfl_up(inc, d, 64);
        if (lane >= d) inc += x;
    }
    if (lane == 63) wsum[wid] = inc;
    __syncthreads();
    int off = 0;
#pragma unroll
    for (int w = 0; w < 8; ++w) off += (w < wid) ? wsum[w] : 0;
    int pexcl = off + inc - len;
    if (t < nchunks) { runsum[t] = pexcl; rbase[t] = t * PCHUNK + cb; }
    if (t == 511) runsum[nchunks] = off + inc;   // grand total
    __syncthreads();
    int total = runsum[nchunks];

    int n = t >> 2, q = t & 3;        // owner: node n (0..127), slice q (0..3)
    int node = node0 + n;
    bool nv = (n < NPB) && (node < n_right);

    float we[16];
#pragma unroll
    for (int j = 0; j < 16; ++j) we[j] = We[j];

    float rv[16];
    if (nv) {
        const uint4* rp = (const uint4*)(Rpk + (size_t)node * 8);
        uint4 ra = rp[0], rb = rp[1];
        u32 w0 = ra.x, w1 = ra.y, w2 = ra.z, w3 = ra.w;
        u32 w4 = rb.x, w5 = rb.y, w6 = rb.z, w7 = rb.w;
        rv[0] = __uint_as_float(w0 << 16); rv[8]  = __uint_as_float(w0 & 0xffff0000u);
        rv[1] = __uint_as_float(w1 << 16); rv[9]  = __uint_as_float(w1 & 0xffff0000u);
        rv[2] = __uint_as_float(w2 << 16); rv[10] = __uint_as_float(w2 & 0xffff0000u);
        rv[3] = __uint_as_float(w3 << 16); rv[11] = __uint_as_float(w3 & 0xffff0000u);
        rv[4] = __uint_as_float(w4 << 16); rv[12] = __uint_as_float(w4 & 0xffff0000u);
        rv[5] = __uint_as_float(w5 << 16); rv[13] = __uint_as_float(w5 & 0xffff0000u);
        rv[6] = __uint_as_float(w6 << 16); rv[14] = __uint_as_float(w6 & 0xffff0000u);
        rv[7] = __uint_as_float(w7 << 16); rv[15] = __uint_as_float(w7 & 0xffff0000u);
    } else {
#pragma unroll
        for (int j = 0; j < 16; ++j) rv[j] = 0.0f;
    }

    float acc[16];
#pragma unroll
    for (int j = 0; j < 16; ++j) acc[j] = 0.0f;
    int dsum = 0;

    for (int tile0 = 0; tile0 < total; tile0 += REC_CAP) {
        int m = total - tile0; if (m > REC_CAP) m = REC_CAP;
        u64 rcl[RPT];
        int rnk[RPT];
        if (t < NHIST) hist[t] = 0;
        // addr-translation table: one thread per run, contiguous writes
        for (int r = t; r < nchunks; r += 512) {
            int g_lo = runsum[r], g_hi = runsum[r + 1];
            int lo = g_lo > tile0 ? g_lo : tile0;
            int hi = g_hi < tile0 + m ? g_hi : tile0 + m;
            int a = rbase[r] + (lo - g_lo);
            for (int g = lo; g < hi; ++g, ++a) addrtab[g - tile0] = (u32)a;
        }
        __syncthreads();
        // strided coalesced loads into registers (rec read once)
#pragma unroll
        for (int k = 0; k < RPT; ++k) {
            int i = t + k * 512;
            rcl[k] = (i < m) ? rec[(size_t)addrtab[i]] : 0;
        }
        // count: atomic return IS the rank within the node
#pragma unroll
        for (int k = 0; k < RPT; ++k) {
            int i = t + k * 512;
            rnk[k] = (i < m) ? atomicAdd(&hist[(int)(rcl[k] & 0xffu)], 1) : 0;
        }
        __syncthreads();
        // exclusive scan over 128 counts: single wave, shfl scan
        if (t < 64) {
            int h0 = hist[2 * t], h1 = hist[2 * t + 1];
            int s2 = h0 + h1;
            int inc2 = s2;
#pragma unroll
            for (int d = 1; d < 64; d <<= 1) {
                int x = __shfl_up(inc2, d, 64);
                if (t >= d) inc2 += x;
            }
            int ex = inc2 - s2;
            base_[2 * t] = ex;
            base_[2 * t + 1] = ex + h0;
        }
        __syncthreads();
        // scatter: position = base + rank, plain LDS write
#pragma unroll
        for (int k = 0; k < RPT; ++k) {
            int i = t + k * 512;
            if (i < m) srec[base_[(int)(rcl[k] & 0xffu)] + rnk[k]] = rcl[k];
        }
        __syncthreads();
        // owner phase: 4 threads per node, register accumulate
        {
            int cc = nv ? hist[n] : 0;
            int b0_ = nv ? base_[n] : 0;
            if (q == 0) dsum += cc;
            for (int k = q; k < cc; k += 4) {
                u64 rc = srec[b0_ + k];
                int l = (int)((rc >> 8) & 0xFFFFFFu);
                float f = __uint_as_float((u32)(rc >> 32));
                const uint4* lp = (const uint4*)(Lpk + (size_t)l * 8);
                uint4 la = lp[0], lb = lp[1];
                u32 w0 = la.x, w1 = la.y, w2 = la.z, w3 = la.w;
                u32 w4 = lb.x, w5 = lb.y, w6 = lb.z, w7 = lb.w;
#define PAIR(h, lw) { \
                float l0 = __uint_as_float(lw << 16); \
                float l1 = __uint_as_float(lw & 0xffff0000u); \
                acc[h]     += fmaxf(fmaf(f, we[h], l0) + rv[h], 0.0f); \
                acc[h + 8] += fmaxf(fmaf(f, we[h + 8], l1) + rv[h + 8], 0.0f); }
                PAIR(0, w0) PAIR(1, w1) PAIR(2, w2) PAIR(3, w3)
                PAIR(4, w4) PAIR(5, w5) PAIR(6, w6) PAIR(7, w7)
#undef PAIR
            }
        }
        __syncthreads();
    }

    // combine the 4 owner slices (lanes 4n..4n+3 in the same wave)
#pragma unroll
    for (int j = 0; j < 16; ++j) {
        acc[j] += __shfl_xor(acc[j], 1, 64);
        acc[j] += __shfl_xor(acc[j], 2, 64);
    }
    dsum += __shfl_xor(dsum, 1, 64);
    dsum += __shfl_xor(dsum, 2, 64);

    // ---- fused per-node epilogue (all 4 owners compute; write quarters) ----
    if (nv) {
        float rfx[16];
        const float4* Rf = (const float4*)(rf + (size_t)node * EMB);
#pragma unroll
        for (int k = 0; k < 4; ++k) {
            float4 w = Rf[k];
            rfx[4 * k] = w.x; rfx[4 * k + 1] = w.y; rfx[4 * k + 2] = w.z; rfx[4 * k + 3] = w.w;
        }
        float c = (float)dsum;
        float x[16], y[16], z[16], o[16];
#pragma unroll
        for (int j = 0; j < 16; ++j) {
            float a = c * sb[j];
#pragma unroll
            for (int k = 0; k < 16; ++k) a = fmaf(acc[k], sWf[k * 16 + j], a);
            x[j] = fmaxf(a, 0.0f);
        }
#pragma unroll
        for (int j = 0; j < 16; ++j) {
            float a = sb[16 + j];
#pragma unroll
            for (int k = 0; k < 16; ++k) a = fmaf(x[k], sWp[k * 16 + j], a);
            y[j] = a;
        }
#pragma unroll
        for (int j = 0; j < 16; ++j) {
            float a = sb[32 + j];
#pragma unroll
            for (int k = 0; k < 16; ++k) a = fmaf(y[k], sWo1[k * 16 + j], a);
#pragma unroll
            for (int k = 0; k < 16; ++k) a = fmaf(rfx[k], sWo1[(16 + k) * 16 + j], a);
            z[j] = fmaxf(a, 0.0f);
        }
#pragma unroll
        for (int j = 0; j < 16; ++j) {
            float a = sb[48 + j];
#pragma unroll
            for (int k = 0; k < 16; ++k) a = fmaf(z[k], sWo2[k * 16 + j], a);
            o[j] = a;
        }
        float4* Op = (float4*)(out + (size_t)node * EMB);
        Op[q] = make_float4(o[q * 4], o[q * 4 + 1], o[q * 4 + 2], o[q * 4 + 3]);
    }
}

// ---------------- fallback atomic edge kernel (f32 tables) ----------------
__global__ void edge_kernel(const int* __restrict__ eidx, const float* __restrict__ ef,
                            const float* __restrict__ L, const float* __restrict__ R,
                            const float* __restrict__ We, float* __restrict__ S,
                            int* __restrict__ cnt, int E) {
    long long tid = (long long)blockIdx.x * blockDim.x + threadIdx.x;
    int e = (int)(tid >> 4);
    int j = (int)(tid & 15);
    if (e >= E) return;
    int l = eidx[e];
    int r = eidx[E + e];
    float v = L[(size_t)l * EMB + j] + ef[e] * We[j] + R[(size_t)r * EMB + j];
    v = fmaxf(v, 0.0f);
    unsafeAtomicAdd(&S[(size_t)r * EMB + j], v);
    if (j == 0) atomicAdd(&cnt[r], 1);
}

// ---------------- standalone epilogue (fallback path only) ----------------
__global__ void final_kernel(const float* __restrict__ S, const int* __restrict__ deg,
                             const float* __restrict__ rf,
                             const float* __restrict__ Wf, const float* __restrict__ bf,
                             const float* __restrict__ Wp, const float* __restrict__ bp,
                             const float* __restrict__ Wo1, const float* __restrict__ bo1,
                             const float* __restrict__ Wo2, const float* __restrict__ bo2,
                             float* __restrict__ out, int N) {
    __shared__ float sWf[256], sWp[256], sWo1[512], sWo2[256];
    __shared__ float sb[64];
    int t = threadIdx.x;
    for (int i = t; i < 256; i += 256) { sWf[i] = Wf[i]; sWp[i] = Wp[i]; sWo2[i] = Wo2[i]; }
    for (int i = t; i < 512; i += 256) sWo1[i] = Wo1[i];
    if (t < 16) { sb[t] = bf[t]; sb[16 + t] = bp[t]; sb[32 + t] = bo1[t]; sb[48 + t] = bo2[t]; }
    __syncthreads();

    int r = blockIdx.x * blockDim.x + t;
    if (r >= N) return;

    float s[16], x[16], y[16], rv[16], z[16], o[16];
    const float4* Sp = (const float4*)(S + (size_t)r * EMB);
    const float4* Rp = (const float4*)(rf + (size_t)r * EMB);
#pragma unroll
    for (int k = 0; k < 4; ++k) {
        float4 v = Sp[k];
        s[4 * k] = v.x; s[4 * k + 1] = v.y; s[4 * k + 2] = v.z; s[4 * k + 3] = v.w;
        float4 w = Rp[k];
        rv[4 * k] = w.x; rv[4 * k + 1] = w.y; rv[4 * k + 2] = w.z; rv[4 * k + 3] = w.w;
    }
    float c = (float)deg[r];

#pragma unroll
    for (int j = 0; j < 16; ++j) {
        float a = c * sb[j];
#pragma unroll
        for (int k = 0; k < 16; ++k) a = fmaf(s[k], sWf[k * 16 + j], a);
        x[j] = fmaxf(a, 0.0f);
    }
#pragma unroll
    for (int j = 0; j < 16; ++j) {
        float a = sb[16 + j];
#pragma unroll
        for (int k = 0; k < 16; ++k) a = fmaf(x[k], sWp[k * 16 + j], a);
        y[j] = a;
    }
#pragma unroll
    for (int j = 0; j < 16; ++j) {
        float a = sb[32 + j];
#pragma unroll
        for (int k = 0; k < 16; ++k) a = fmaf(y[k], sWo1[k * 16 + j], a);
#pragma unroll
        for (int k = 0; k < 16; ++k) a = fmaf(rv[k], sWo1[(16 + k) * 16 + j], a);
        z[j] = fmaxf(a, 0.0f);
    }
#pragma unroll
    for (int j = 0; j < 16; ++j) {
        float a = sb[48 + j];
#pragma unroll
        for (int k = 0; k < 16; ++k) a = fmaf(z[k], sWo2[k * 16 + j], a);
        o[j] = a;
    }
    float4* Op = (float4*)(out + (size_t)r * EMB);
#pragma unroll
    for (int k = 0; k < 4; ++k)
        Op[k] = make_float4(o[4 * k], o[4 * k + 1], o[4 * k + 2], o[4 * k + 3]);
}

extern "C" void kernel_launch(void* const* d_in, const int* in_sizes, int n_in,
                              void* d_out, int out_size, void* d_ws, size_t ws_size,
                              hipStream_t stream) {
    const float* lf     = (const float*)d_in[0];
    const int*   eidx   = (const int*)d_in[1];
    const float* ef     = (const float*)d_in[2];
    const float* rf     = (const float*)d_in[3];
    const float* W_left = (const float*)d_in[4];
    const float* b_left = (const float*)d_in[5];
    const float* W_edge = (const float*)d_in[6];
    const float* W_right= (const float*)d_in[7];
    const float* W_final= (const float*)d_in[8];
    const float* b_final= (const float*)d_in[9];
    const float* W_post = (const float*)d_in[10];
    const float* b_post = (const float*)d_in[11];
    const float* W_out1 = (const float*)d_in[12];
    const float* b_out1 = (const float*)d_in[13];
    const float* W_out2 = (const float*)d_in[14];
    const float* b_out2 = (const float*)d_in[15];

    int n_left  = in_sizes[0] / EMB;
    int E       = in_sizes[2];
    int n_right = in_sizes[3] / EMB;
    float* out = (float*)d_out;

    int NB = (n_right + NPB - 1) / NPB;
    int nchunks = (E + PCHUNK - 1) / PCHUNK;

    size_t need = (size_t)E * 8                        // rec
                + (size_t)NB * nchunks * 8             // cbM (int2)
                + ((size_t)n_left + n_right) * 32;     // Lpk, Rpk

    if (ws_size >= need && NB <= MAXNB && nchunks <= MAXCHUNKS) {
        u64*  rec = (u64*)d_ws;
        int2* cbM = (int2*)(rec + (size_t)E);
        u32*  Lpk = (u32*)(cbM + (size_t)NB * nchunks);
        u32*  Rpk = Lpk + (size_t)n_left * 8;

        linear16_pack_kernel<<<(n_left * 8 + 255) / 256, 256, 0, stream>>>(lf, W_left, b_left, Lpk, n_left);
        linear16_pack_kernel<<<(n_right * 8 + 255) / 256, 256, 0, stream>>>(rf, W_right, nullptr, Rpk, n_right);

        chunk_sort_kernel<<<nchunks, 512, 0, stream>>>(eidx, ef, rec, cbM, E, NB, nchunks);

        bucket_gather_kernel<<<NB, 512, 0, stream>>>(rec, cbM, Lpk, Rpk, W_edge, rf,
                                                     W_final, b_final, W_post, b_post,
                                                     W_out1, b_out1, W_out2, b_out2,
                                                     out, n_right, NB, nchunks);
    } else {
        float* L   = (float*)d_ws;
        float* R   = L + (size_t)n_left * EMB;
        float* S   = R + (size_t)n_right * EMB;
        int*   cnt = (int*)(S + (size_t)n_right * EMB);

        zero_f32<<<2048, 256, 0, stream>>>(S, (size_t)n_right * EMB);
        zero_i32<<<(n_right + 255) / 256, 256, 0, stream>>>(cnt, n_right);

        linear16_kernel<<<(n_left * EMB + 255) / 256, 256, 0, stream>>>(lf, W_left, b_left, L, n_left);
        linear16_kernel<<<(n_right * EMB + 255) / 256, 256, 0, stream>>>(rf, W_right, nullptr, R, n_right);

        long long ethreads = (long long)E * EMB;
        edge_kernel<<<(unsigned)((ethreads + 255) / 256), 256, 0, stream>>>(eidx, ef, L, R, W_edge, S, cnt, E);

        final_kernel<<<(n_right + 255) / 256, 256, 0, stream>>>(S, cnt, rf,
            W_final, b_final, W_post, b_post, W_out1, b_out1, W_out2, b_out2, out, n_right);
    }
}

// Round 21
// 86.650 us; speedup vs baseline: 1.2112x; 1.2112x over previous
//
#include <hip/hip_runtime.h>

#define EMB 16
#define NPB 196               // right-nodes per bucket (NB ~ 511)
#define BNODES 256            // padded per-node hist (rl < NPB < 256)
#define MAXNB 512
#define PCHUNK 6656           // edges per chunk-sort block (13 * 512)
#define RPTC 13               // PCHUNK / 512
#define MAXCHUNKS 512
#define REC_CAP 2048          // records per gather LDS tile
#define RPT 4                 // REC_CAP / 512
typedef unsigned int u32;
typedef unsigned long long u64;

__global__ void zero_f32(float* __restrict__ p, size_t n) {
    size_t i = (size_t)blockIdx.x * blockDim.x + threadIdx.x;
    size_t stride = (size_t)gridDim.x * blockDim.x;
    for (; i < n; i += stride) p[i] = 0.0f;
}

__global__ void zero_i32(int* __restrict__ p, int n) {
    int i = blockIdx.x * blockDim.x + threadIdx.x;
    if (i < n) p[i] = 0;
}

__device__ __forceinline__ u32 bf16bits_rne(float x) {
    u32 u = __float_as_uint(x);
    return (u + 0x7fffu + ((u >> 16) & 1u)) >> 16;
}

// Packed bf16 linear: Y[row*8+h] = pack(bf16(row@W[:,h+8]+b), bf16(row@W[:,h]+b))
__global__ void linear16_pack_kernel(const float* __restrict__ X, const float* __restrict__ W,
                                     const float* __restrict__ b, u32* __restrict__ Y, int N) {
    int tid = blockIdx.x * blockDim.x + threadIdx.x;
    int row = tid >> 3;
    int h = tid & 7;
    if (row >= N) return;
    float a0 = b ? b[h] : 0.0f;
    float a1 = b ? b[h + 8] : 0.0f;
    const float* xr = X + (size_t)row * EMB;
#pragma unroll
    for (int k = 0; k < EMB; ++k) {
        float xv = xr[k];
        a0 = fmaf(xv, W[k * EMB + h], a0);
        a1 = fmaf(xv, W[k * EMB + h + 8], a1);
    }
    Y[(size_t)row * 8 + h] = (bf16bits_rne(a1) << 16) | bf16bits_rne(a0);
}

// Plain f32 linear (fallback path)
__global__ void linear16_kernel(const float* __restrict__ X, const float* __restrict__ W,
                                const float* __restrict__ b, float* __restrict__ Y, int N) {
    int tid = blockIdx.x * blockDim.x + threadIdx.x;
    int row = tid >> 4;
    int j = tid & 15;
    if (row >= N) return;
    float acc = b ? b[j] : 0.0f;
    const float* xr = X + (size_t)row * EMB;
#pragma unroll
    for (int k = 0; k < EMB; ++k) acc = fmaf(xr[k], W[k * EMB + j], acc);
    Y[(size_t)row * EMB + j] = acc;
}

// ---------------- chunk-sort: single read pass; bucket-major int2 cnt/base ----
// Record: [f:32][l:24][rl:8]; cbM[b*nchunks+c] = {cnt, cbase}
__launch_bounds__(512)
__global__ void chunk_sort_kernel(const int* __restrict__ eidx, const float* __restrict__ ef,
                                  u64* __restrict__ rec, int2* __restrict__ cbM,
                                  int E, int NB, int nchunks) {
    __shared__ u64 srec[PCHUNK];   // 52 KB
    __shared__ int hist[MAXNB];    // counts -> bases
    __shared__ int wsum[8];
    int t = threadIdx.x;
    int lane = t & 63, wid = t >> 6;
    int c = blockIdx.x;
    long long base = (long long)c * PCHUNK;
    int n = (int)(((long long)E - base) < PCHUNK ? ((long long)E - base) : PCHUNK);
    const int* ridx = eidx + E;

    for (int i = t; i < NB; i += 512) hist[i] = 0;
    __syncthreads();
    // single load pass: build record + rank in registers
    u64 rcv[RPTC];
    int pk[RPTC];   // (bb << 13) | rank
#pragma unroll
    for (int k = 0; k < RPTC; ++k) {
        int i = t + k * 512;
        rcv[k] = 0; pk[k] = 0;
        if (i < n) {
            int r = ridx[base + i];
            int l = eidx[base + i];
            float f = ef[base + i];
            int bb = r / NPB;
            int rl = r - bb * NPB;
            int rank = atomicAdd(&hist[bb], 1);
            rcv[k] = ((u64)__float_as_uint(f) << 32) | ((u64)(u32)l << 8) | (u32)rl;
            pk[k] = (bb << 13) | rank;
        }
    }
    __syncthreads();
    // hierarchical wave scan over NB counts (1 barrier)
    int v = (t < NB) ? hist[t] : 0;
    int inc = v;
#pragma unroll
    for (int d = 1; d < 64; d <<= 1) {
        int x = __shfl_up(inc, d, 64);
        if (lane >= d) inc += x;
    }
    if (lane == 63) wsum[wid] = inc;
    __syncthreads();
    int off = 0;
#pragma unroll
    for (int w = 0; w < 8; ++w) off += (w < wid) ? wsum[w] : 0;
    int ex = off + inc - v;   // exclusive prefix
    if (t < NB) {
        cbM[(size_t)t * nchunks + c] = make_int2(v, ex);   // bucket-major (scattered 8B store)
        hist[t] = ex;      // base
    }
    __syncthreads();
    // scatter: position = base + rank, plain LDS write
#pragma unroll
    for (int k = 0; k < RPTC; ++k) {
        int i = t + k * 512;
        if (i < n) srec[hist[pk[k] >> 13] + (pk[k] & 8191)] = rcv[k];
    }
    __syncthreads();
    for (int i = t; i < n; i += 512) rec[base + i] = srec[i];
}

// ---------------- gather + fused per-node epilogue ----------------
__launch_bounds__(512)
__global__ void bucket_gather_kernel(const u64* __restrict__ rec, const int2* __restrict__ cbM,
                                     const u32* __restrict__ Lpk, const u32* __restrict__ Rpk,
                                     const float* __restrict__ We, const float* __restrict__ rf,
                                     const float* __restrict__ Wf, const float* __restrict__ bf,
                                     const float* __restrict__ Wp, const float* __restrict__ bp,
                                     const float* __restrict__ Wo1, const float* __restrict__ bo1,
                                     const float* __restrict__ Wo2, const float* __restrict__ bo2,
                                     float* __restrict__ out,
                                     int n_right, int NB, int nchunks) {
    __shared__ u64 srec[REC_CAP];                 // 16 KB
    __shared__ u32 addrtab[REC_CAP];              // 8 KB
    __shared__ int runsum[MAXCHUNKS + 1];         // 2 KB
    __shared__ int rbase[MAXCHUNKS];              // 2 KB
    __shared__ int hist[BNODES], base_[BNODES];   // 2 KB
    __shared__ int wsum[8];
    __shared__ float sWf[256], sWp[256], sWo1[512], sWo2[256], sb[64];  // 5.3 KB
    int b = blockIdx.x;
    int t = threadIdx.x;
    int lane = t & 63, wid = t >> 6;
    int node0 = b * NPB;

    // stage epilogue weights (covered by the scan's barrier)
    if (t < 256) { sWf[t] = Wf[t]; sWp[t] = Wp[t]; sWo2[t] = Wo2[t]; }
    sWo1[t] = Wo1[t];
    if (t < 16) { sb[t] = bf[t]; sb[16 + t] = bp[t]; sb[32 + t] = bo1[t]; sb[48 + t] = bo2[t]; }

    // contiguous int2 run-table read + hierarchical wave scan (1 barrier)
    int len = 0, cb = 0;
    if (t < nchunks) { int2 v = cbM[(size_t)b * nchunks + t]; len = v.x; cb = v.y; }
    int inc = len;
#pragma unroll
    for (int d = 1; d < 64; d <<= 1) {
        int x = __shfl_up(inc, d, 64);
        if (lane >= d) inc += x;
    }
    if (lane == 63) wsum[wid] = inc;
    __syncthreads();
    int off = 0;
#pragma unroll
    for (int w = 0; w < 8; ++w) off += (w < wid) ? wsum[w] : 0;
    int pexcl = off + inc - len;
    if (t < nchunks) { runsum[t] = pexcl; rbase[t] = t * PCHUNK + cb; }
    if (t == 511) runsum[nchunks] = off + inc;   // grand total
    __syncthreads();
    int total = runsum[nchunks];

    int n = t >> 1, q = t & 1;        // owner: node n, slice q (0..1)
    int node = node0 + n;
    bool nv = (n < NPB) && (node < n_right);

    float we[16];
#pragma unroll
    for (int j = 0; j < 16; ++j) we[j] = We[j];

    float rv[16];
    if (nv) {
        const uint4* rp = (const uint4*)(Rpk + (size_t)node * 8);
        uint4 ra = rp[0], rb = rp[1];
        u32 w0 = ra.x, w1 = ra.y, w2 = ra.z, w3 = ra.w;
        u32 w4 = rb.x, w5 = rb.y, w6 = rb.z, w7 = rb.w;
        rv[0] = __uint_as_float(w0 << 16); rv[8]  = __uint_as_float(w0 & 0xffff0000u);
        rv[1] = __uint_as_float(w1 << 16); rv[9]  = __uint_as_float(w1 & 0xffff0000u);
        rv[2] = __uint_as_float(w2 << 16); rv[10] = __uint_as_float(w2 & 0xffff0000u);
        rv[3] = __uint_as_float(w3 << 16); rv[11] = __uint_as_float(w3 & 0xffff0000u);
        rv[4] = __uint_as_float(w4 << 16); rv[12] = __uint_as_float(w4 & 0xffff0000u);
        rv[5] = __uint_as_float(w5 << 16); rv[13] = __uint_as_float(w5 & 0xffff0000u);
        rv[6] = __uint_as_float(w6 << 16); rv[14] = __uint_as_float(w6 & 0xffff0000u);
        rv[7] = __uint_as_float(w7 << 16); rv[15] = __uint_as_float(w7 & 0xffff0000u);
    } else {
#pragma unroll
        for (int j = 0; j < 16; ++j) rv[j] = 0.0f;
    }

    float acc[16];
#pragma unroll
    for (int j = 0; j < 16; ++j) acc[j] = 0.0f;
    int dsum = 0;

    for (int tile0 = 0; tile0 < total; tile0 += REC_CAP) {
        int m = total - tile0; if (m > REC_CAP) m = REC_CAP;
        u64 rcl[RPT];
        int rnk[RPT];
        if (t < BNODES) hist[t] = 0;
        // addr-translation table: one thread per run, contiguous writes
        for (int r = t; r < nchunks; r += 512) {
            int g_lo = runsum[r], g_hi = runsum[r + 1];
            int lo = g_lo > tile0 ? g_lo : tile0;
            int hi = g_hi < tile0 + m ? g_hi : tile0 + m;
            int a = rbase[r] + (lo - g_lo);
            for (int g = lo; g < hi; ++g, ++a) addrtab[g - tile0] = (u32)a;
        }
        __syncthreads();
        // strided coalesced loads into registers (rec read once)
#pragma unroll
        for (int k = 0; k < RPT; ++k) {
            int i = t + k * 512;
            rcl[k] = (i < m) ? rec[(size_t)addrtab[i]] : 0;
        }
        // count: atomic return IS the rank within the node
#pragma unroll
        for (int k = 0; k < RPT; ++k) {
            int i = t + k * 512;
            rnk[k] = (i < m) ? atomicAdd(&hist[(int)(rcl[k] & 0xffu)], 1) : 0;
        }
        __syncthreads();
        // exclusive scan over 256 counts: single wave, shfl scan
        if (t < 64) {
            int h0 = hist[4 * t], h1 = hist[4 * t + 1], h2 = hist[4 * t + 2], h3 = hist[4 * t + 3];
            int s4 = h0 + h1 + h2 + h3;
            int inc4 = s4;
#pragma unroll
            for (int d = 1; d < 64; d <<= 1) {
                int x = __shfl_up(inc4, d, 64);
                if (t >= d) inc4 += x;
            }
            int ex = inc4 - s4;
            base_[4 * t] = ex;
            base_[4 * t + 1] = ex + h0;
            base_[4 * t + 2] = ex + h0 + h1;
            base_[4 * t + 3] = ex + h0 + h1 + h2;
        }
        __syncthreads();
        // scatter: position = base + rank, plain LDS write
#pragma unroll
        for (int k = 0; k < RPT; ++k) {
            int i = t + k * 512;
            if (i < m) srec[base_[(int)(rcl[k] & 0xffu)] + rnk[k]] = rcl[k];
        }
        __syncthreads();
        // owner phase
        {
            int cc = nv ? hist[n] : 0;
            int b0_ = nv ? base_[n] : 0;
            if (q == 0) dsum += cc;
            for (int k = q; k < cc; k += 2) {
                u64 rc = srec[b0_ + k];
                int l = (int)((rc >> 8) & 0xFFFFFFu);
                float f = __uint_as_float((u32)(rc >> 32));
                const uint4* lp = (const uint4*)(Lpk + (size_t)l * 8);
                uint4 la = lp[0], lb = lp[1];
                u32 w0 = la.x, w1 = la.y, w2 = la.z, w3 = la.w;
                u32 w4 = lb.x, w5 = lb.y, w6 = lb.z, w7 = lb.w;
#define PAIR(h, lw) { \
                float l0 = __uint_as_float(lw << 16); \
                float l1 = __uint_as_float(lw & 0xffff0000u); \
                acc[h]     += fmaxf(fmaf(f, we[h], l0) + rv[h], 0.0f); \
                acc[h + 8] += fmaxf(fmaf(f, we[h + 8], l1) + rv[h + 8], 0.0f); }
                PAIR(0, w0) PAIR(1, w1) PAIR(2, w2) PAIR(3, w3)
                PAIR(4, w4) PAIR(5, w5) PAIR(6, w6) PAIR(7, w7)
#undef PAIR
            }
        }
        __syncthreads();
    }

    // combine the 2 owner slices
#pragma unroll
    for (int j = 0; j < 16; ++j) acc[j] += __shfl_xor(acc[j], 1, 64);
    dsum += __shfl_xor(dsum, 1, 64);

    // ---- fused per-node epilogue ----
    if (nv) {
        float rfx[16];
        const float4* Rf = (const float4*)(rf + (size_t)node * EMB);
#pragma unroll
        for (int k = 0; k < 4; ++k) {
            float4 w = Rf[k];
            rfx[4 * k] = w.x; rfx[4 * k + 1] = w.y; rfx[4 * k + 2] = w.z; rfx[4 * k + 3] = w.w;
        }
        float c = (float)dsum;
        float x[16], y[16], z[16], o[16];
#pragma unroll
        for (int j = 0; j < 16; ++j) {
            float a = c * sb[j];
#pragma unroll
            for (int k = 0; k < 16; ++k) a = fmaf(acc[k], sWf[k * 16 + j], a);
            x[j] = fmaxf(a, 0.0f);
        }
#pragma unroll
        for (int j = 0; j < 16; ++j) {
            float a = sb[16 + j];
#pragma unroll
            for (int k = 0; k < 16; ++k) a = fmaf(x[k], sWp[k * 16 + j], a);
            y[j] = a;
        }
#pragma unroll
        for (int j = 0; j < 16; ++j) {
            float a = sb[32 + j];
#pragma unroll
            for (int k = 0; k < 16; ++k) a = fmaf(y[k], sWo1[k * 16 + j], a);
#pragma unroll
            for (int k = 0; k < 16; ++k) a = fmaf(rfx[k], sWo1[(16 + k) * 16 + j], a);
            z[j] = fmaxf(a, 0.0f);
        }
#pragma unroll
        for (int j = 0; j < 16; ++j) {
            float a = sb[48 + j];
#pragma unroll
            for (int k = 0; k < 16; ++k) a = fmaf(z[k], sWo2[k * 16 + j], a);
            o[j] = a;
        }
        float4* Op = (float4*)(out + (size_t)node * EMB);
        Op[q * 2]     = make_float4(o[q * 8],     o[q * 8 + 1], o[q * 8 + 2], o[q * 8 + 3]);
        Op[q * 2 + 1] = make_float4(o[q * 8 + 4], o[q * 8 + 5], o[q * 8 + 6], o[q * 8 + 7]);
    }
}

// ---------------- fallback atomic edge kernel (f32 tables) ----------------
__global__ void edge_kernel(const int* __restrict__ eidx, const float* __restrict__ ef,
                            const float* __restrict__ L, const float* __restrict__ R,
                            const float* __restrict__ We, float* __restrict__ S,
                            int* __restrict__ cnt, int E) {
    long long tid = (long long)blockIdx.x * blockDim.x + threadIdx.x;
    int e = (int)(tid >> 4);
    int j = (int)(tid & 15);
    if (e >= E) return;
    int l = eidx[e];
    int r = eidx[E + e];
    float v = L[(size_t)l * EMB + j] + ef[e] * We[j] + R[(size_t)r * EMB + j];
    v = fmaxf(v, 0.0f);
    unsafeAtomicAdd(&S[(size_t)r * EMB + j], v);
    if (j == 0) atomicAdd(&cnt[r], 1);
}

// ---------------- standalone epilogue (fallback path only) ----------------
__global__ void final_kernel(const float* __restrict__ S, const int* __restrict__ deg,
                             const float* __restrict__ rf,
                             const float* __restrict__ Wf, const float* __restrict__ bf,
                             const float* __restrict__ Wp, const float* __restrict__ bp,
                             const float* __restrict__ Wo1, const float* __restrict__ bo1,
                             const float* __restrict__ Wo2, const float* __restrict__ bo2,
                             float* __restrict__ out, int N) {
    __shared__ float sWf[256], sWp[256], sWo1[512], sWo2[256];
    __shared__ float sb[64];
    int t = threadIdx.x;
    for (int i = t; i < 256; i += 256) { sWf[i] = Wf[i]; sWp[i] = Wp[i]; sWo2[i] = Wo2[i]; }
    for (int i = t; i < 512; i += 256) sWo1[i] = Wo1[i];
    if (t < 16) { sb[t] = bf[t]; sb[16 + t] = bp[t]; sb[32 + t] = bo1[t]; sb[48 + t] = bo2[t]; }
    __syncthreads();

    int r = blockIdx.x * blockDim.x + t;
    if (r >= N) return;

    float s[16], x[16], y[16], rv[16], z[16], o[16];
    const float4* Sp = (const float4*)(S + (size_t)r * EMB);
    const float4* Rp = (const float4*)(rf + (size_t)r * EMB);
#pragma unroll
    for (int k = 0; k < 4; ++k) {
        float4 v = Sp[k];
        s[4 * k] = v.x; s[4 * k + 1] = v.y; s[4 * k + 2] = v.z; s[4 * k + 3] = v.w;
        float4 w = Rp[k];
        rv[4 * k] = w.x; rv[4 * k + 1] = w.y; rv[4 * k + 2] = w.z; rv[4 * k + 3] = w.w;
    }
    float c = (float)deg[r];

#pragma unroll
    for (int j = 0; j < 16; ++j) {
        float a = c * sb[j];
#pragma unroll
        for (int k = 0; k < 16; ++k) a = fmaf(s[k], sWf[k * 16 + j], a);
        x[j] = fmaxf(a, 0.0f);
    }
#pragma unroll
    for (int j = 0; j < 16; ++j) {
        float a = sb[16 + j];
#pragma unroll
        for (int k = 0; k < 16; ++k) a = fmaf(x[k], sWp[k * 16 + j], a);
        y[j] = a;
    }
#pragma unroll
    for (int j = 0; j < 16; ++j) {
        float a = sb[32 + j];
#pragma unroll
        for (int k = 0; k < 16; ++k) a = fmaf(y[k], sWo1[k * 16 + j], a);
#pragma unroll
        for (int k = 0; k < 16; ++k) a = fmaf(rv[k], sWo1[(16 + k) * 16 + j], a);
        z[j] = fmaxf(a, 0.0f);
    }
#pragma unroll
    for (int j = 0; j < 16; ++j) {
        float a = sb[48 + j];
#pragma unroll
        for (int k = 0; k < 16; ++k) a = fmaf(z[k], sWo2[k * 16 + j], a);
        o[j] = a;
    }
    float4* Op = (float4*)(out + (size_t)r * EMB);
#pragma unroll
    for (int k = 0; k < 4; ++k)
        Op[k] = make_float4(o[4 * k], o[4 * k + 1], o[4 * k + 2], o[4 * k + 3]);
}

extern "C" void kernel_launch(void* const* d_in, const int* in_sizes, int n_in,
                              void* d_out, int out_size, void* d_ws, size_t ws_size,
                              hipStream_t stream) {
    const float* lf     = (const float*)d_in[0];
    const int*   eidx   = (const int*)d_in[1];
    const float* ef     = (const float*)d_in[2];
    const float* rf     = (const float*)d_in[3];
    const float* W_left = (const float*)d_in[4];
    const float* b_left = (const float*)d_in[5];
    const float* W_edge = (const float*)d_in[6];
    const float* W_right= (const float*)d_in[7];
    const float* W_final= (const float*)d_in[8];
    const float* b_final= (const float*)d_in[9];
    const float* W_post = (const float*)d_in[10];
    const float* b_post = (const float*)d_in[11];
    const float* W_out1 = (const float*)d_in[12];
    const float* b_out1 = (const float*)d_in[13];
    const float* W_out2 = (const float*)d_in[14];
    const float* b_out2 = (const float*)d_in[15];

    int n_left  = in_sizes[0] / EMB;
    int E       = in_sizes[2];
    int n_right = in_sizes[3] / EMB;
    float* out = (float*)d_out;

    int NB = (n_right + NPB - 1) / NPB;
    int nchunks = (E + PCHUNK - 1) / PCHUNK;

    size_t need = (size_t)E * 8                        // rec
                + (size_t)NB * nchunks * 8             // cbM (int2)
                + ((size_t)n_left + n_right) * 32;     // Lpk, Rpk

    if (ws_size >= need && NB <= MAXNB && nchunks <= MAXCHUNKS) {
        u64*  rec = (u64*)d_ws;
        int2* cbM = (int2*)(rec + (size_t)E);
        u32*  Lpk = (u32*)(cbM + (size_t)NB * nchunks);
        u32*  Rpk = Lpk + (size_t)n_left * 8;

        linear16_pack_kernel<<<(n_left * 8 + 255) / 256, 256, 0, stream>>>(lf, W_left, b_left, Lpk, n_left);
        linear16_pack_kernel<<<(n_right * 8 + 255) / 256, 256, 0, stream>>>(rf, W_right, nullptr, Rpk, n_right);

        chunk_sort_kernel<<<nchunks, 512, 0, stream>>>(eidx, ef, rec, cbM, E, NB, nchunks);

        bucket_gather_kernel<<<NB, 512, 0, stream>>>(rec, cbM, Lpk, Rpk, W_edge, rf,
                                                     W_final, b_final, W_post, b_post,
                                                     W_out1, b_out1, W_out2, b_out2,
                                                     out, n_right, NB, nchunks);
    } else {
        float* L   = (float*)d_ws;
        float* R   = L + (size_t)n_left * EMB;
        float* S   = R + (size_t)n_right * EMB;
        int*   cnt = (int*)(S + (size_t)n_right * EMB);

        zero_f32<<<2048, 256, 0, stream>>>(S, (size_t)n_right * EMB);
        zero_i32<<<(n_right + 255) / 256, 256, 0, stream>>>(cnt, n_right);

        linear16_kernel<<<(n_left * EMB + 255) / 256, 256, 0, stream>>>(lf, W_left, b_left, L, n_left);
        linear16_kernel<<<(n_right * EMB + 255) / 256, 256, 0, stream>>>(rf, W_right, nullptr, R, n_right);

        long long ethreads = (long long)E * EMB;
        edge_kernel<<<(unsigned)((ethreads + 255) / 256), 256, 0, stream>>>(eidx, ef, L, R, W_edge, S, cnt, E);

        final_kernel<<<(n_right + 255) / 256, 256, 0, stream>>>(S, cnt, rf,
            W_final, b_final, W_post, b_post, W_out1, b_out1, W_out2, b_out2, out, n_right);
    }
}

// Round 22
// 79.342 us; speedup vs baseline: 1.3227x; 1.0921x over previous
//
#include <hip/hip_runtime.h>

#define EMB 16
#define NPB 196               // right-nodes per bucket (NB ~ 511)
#define BNODES 256            // padded per-node hist (rl < NPB < 256)
#define MAXNB 512
#define PCHUNK 6656           // edges per chunk-sort block (13 * 512)
#define RPTC 13               // PCHUNK / 512
#define MAXCHUNKS 512
#define REC_CAP 2048          // records per gather LDS tile
#define RPT 4                 // REC_CAP / 512
typedef unsigned int u32;
typedef unsigned long long u64;

__global__ void zero_f32(float* __restrict__ p, size_t n) {
    size_t i = (size_t)blockIdx.x * blockDim.x + threadIdx.x;
    size_t stride = (size_t)gridDim.x * blockDim.x;
    for (; i < n; i += stride) p[i] = 0.0f;
}

__global__ void zero_i32(int* __restrict__ p, int n) {
    int i = blockIdx.x * blockDim.x + threadIdx.x;
    if (i < n) p[i] = 0;
}

__device__ __forceinline__ u32 bf16bits_rne(float x) {
    u32 u = __float_as_uint(x);
    return (u + 0x7fffu + ((u >> 16) & 1u)) >> 16;
}

// Fused packed bf16 linear for BOTH tables in one launch.
__global__ void pack_both_kernel(const float* __restrict__ lf, const float* __restrict__ rf,
                                 const float* __restrict__ Wl, const float* __restrict__ bl,
                                 const float* __restrict__ Wr,
                                 u32* __restrict__ Lpk, u32* __restrict__ Rpk,
                                 int n_left, int n_right) {
    int tid = blockIdx.x * blockDim.x + threadIdx.x;
    int row = tid >> 3;
    int h = tid & 7;
    if (row >= n_left + n_right) return;
    const float* X; const float* W; const float* bb; u32* Y; int r;
    if (row < n_left) { X = lf; W = Wl; bb = bl; Y = Lpk; r = row; }
    else              { X = rf; W = Wr; bb = nullptr; Y = Rpk; r = row - n_left; }
    float a0 = bb ? bb[h] : 0.0f;
    float a1 = bb ? bb[h + 8] : 0.0f;
    const float* xr = X + (size_t)r * EMB;
#pragma unroll
    for (int k = 0; k < EMB; ++k) {
        float xv = xr[k];
        a0 = fmaf(xv, W[k * EMB + h], a0);
        a1 = fmaf(xv, W[k * EMB + h + 8], a1);
    }
    Y[(size_t)r * 8 + h] = (bf16bits_rne(a1) << 16) | bf16bits_rne(a0);
}

// Plain f32 linear (fallback path)
__global__ void linear16_kernel(const float* __restrict__ X, const float* __restrict__ W,
                                const float* __restrict__ b, float* __restrict__ Y, int N) {
    int tid = blockIdx.x * blockDim.x + threadIdx.x;
    int row = tid >> 4;
    int j = tid & 15;
    if (row >= N) return;
    float acc = b ? b[j] : 0.0f;
    const float* xr = X + (size_t)row * EMB;
#pragma unroll
    for (int k = 0; k < EMB; ++k) acc = fmaf(xr[k], W[k * EMB + j], acc);
    Y[(size_t)row * EMB + j] = acc;
}

// ---------------- chunk-sort: single read pass; bucket-major int2 cnt/base ----
// Record: [f:32][l:24][rl:8]; cbM[b*nchunks+c] = {cnt, cbase}
__launch_bounds__(512)
__global__ void chunk_sort_kernel(const int* __restrict__ eidx, const float* __restrict__ ef,
                                  u64* __restrict__ rec, int2* __restrict__ cbM,
                                  int E, int NB, int nchunks) {
    __shared__ u64 srec[PCHUNK];   // 52 KB
    __shared__ int hist[MAXNB];
    __shared__ int wsum[8];
    int t = threadIdx.x;
    int lane = t & 63, wid = t >> 6;
    int c = blockIdx.x;
    long long base = (long long)c * PCHUNK;
    int n = (int)(((long long)E - base) < PCHUNK ? ((long long)E - base) : PCHUNK);
    const int* ridx = eidx + E;

    for (int i = t; i < NB; i += 512) hist[i] = 0;
    __syncthreads();
    u64 rcv[RPTC];
    int pk[RPTC];   // (bb << 13) | rank
#pragma unroll
    for (int k = 0; k < RPTC; ++k) {
        int i = t + k * 512;
        rcv[k] = 0; pk[k] = 0;
        if (i < n) {
            int r = ridx[base + i];
            int l = eidx[base + i];
            float f = ef[base + i];
            int bb = r / NPB;
            int rl = r - bb * NPB;
            int rank = atomicAdd(&hist[bb], 1);
            rcv[k] = ((u64)__float_as_uint(f) << 32) | ((u64)(u32)l << 8) | (u32)rl;
            pk[k] = (bb << 13) | rank;
        }
    }
    __syncthreads();
    int v = (t < NB) ? hist[t] : 0;
    int inc = v;
#pragma unroll
    for (int d = 1; d < 64; d <<= 1) {
        int x = __shfl_up(inc, d, 64);
        if (lane >= d) inc += x;
    }
    if (lane == 63) wsum[wid] = inc;
    __syncthreads();
    int off = 0;
#pragma unroll
    for (int w = 0; w < 8; ++w) off += (w < wid) ? wsum[w] : 0;
    int ex = off + inc - v;
    if (t < NB) {
        cbM[(size_t)t * nchunks + c] = make_int2(v, ex);
        hist[t] = ex;
    }
    __syncthreads();
#pragma unroll
    for (int k = 0; k < RPTC; ++k) {
        int i = t + k * 512;
        if (i < n) srec[hist[pk[k] >> 13] + (pk[k] & 8191)] = rcv[k];
    }
    __syncthreads();
    for (int i = t; i < n; i += 512) rec[base + i] = srec[i];
}

// ---------------- gather + fused epilogue, software-pipelined tiles ----------
// Tile k+1's rec loads are ISSUED before tile k's owner walk and consumed
// after it: HBM/L2 latency hides under the longest phase. 4 barriers/tile.
__launch_bounds__(512)
__global__ void bucket_gather_kernel(const u64* __restrict__ rec, const int2* __restrict__ cbM,
                                     const u32* __restrict__ Lpk, const u32* __restrict__ Rpk,
                                     const float* __restrict__ We, const float* __restrict__ rf,
                                     const float* __restrict__ Wf, const float* __restrict__ bf,
                                     const float* __restrict__ Wp, const float* __restrict__ bp,
                                     const float* __restrict__ Wo1, const float* __restrict__ bo1,
                                     const float* __restrict__ Wo2, const float* __restrict__ bo2,
                                     float* __restrict__ out,
                                     int n_right, int NB, int nchunks) {
    __shared__ u64 srec[REC_CAP];                 // 16 KB
    __shared__ u32 addrtab[REC_CAP];              // 8 KB
    __shared__ int runsum[MAXCHUNKS + 1];
    __shared__ int rbase[MAXCHUNKS];
    __shared__ int hist[BNODES], base_[BNODES + 1];
    __shared__ int wsum[8];
    __shared__ float sWf[256], sWp[256], sWo1[512], sWo2[256], sb[64];
    int b = blockIdx.x;
    int t = threadIdx.x;
    int lane = t & 63, wid = t >> 6;
    int node0 = b * NPB;

    if (t < 256) { sWf[t] = Wf[t]; sWp[t] = Wp[t]; sWo2[t] = Wo2[t]; }
    sWo1[t] = Wo1[t];
    if (t < 16) { sb[t] = bf[t]; sb[16 + t] = bp[t]; sb[32 + t] = bo1[t]; sb[48 + t] = bo2[t]; }

    // run-table read + hierarchical wave scan (1 barrier)
    int len = 0, cb = 0;
    if (t < nchunks) { int2 v = cbM[(size_t)b * nchunks + t]; len = v.x; cb = v.y; }
    int inc = len;
#pragma unroll
    for (int d = 1; d < 64; d <<= 1) {
        int x = __shfl_up(inc, d, 64);
        if (lane >= d) inc += x;
    }
    if (lane == 63) wsum[wid] = inc;
    __syncthreads();
    int off = 0;
#pragma unroll
    for (int w = 0; w < 8; ++w) off += (w < wid) ? wsum[w] : 0;
    int pexcl = off + inc - len;
    if (t < nchunks) { runsum[t] = pexcl; rbase[t] = t * PCHUNK + cb; }
    if (t == 511) runsum[nchunks] = off + inc;
    if (t < BNODES) hist[t] = 0;
    __syncthreads();
    int total = runsum[nchunks];

    int n = t >> 1, q = t & 1;
    int node = node0 + n;
    bool nv = (n < NPB) && (node < n_right);

    float we[16];
#pragma unroll
    for (int j = 0; j < 16; ++j) we[j] = We[j];

    float rv[16];
    if (nv) {
        const uint4* rp = (const uint4*)(Rpk + (size_t)node * 8);
        uint4 ra = rp[0], rb = rp[1];
        u32 w0 = ra.x, w1 = ra.y, w2 = ra.z, w3 = ra.w;
        u32 w4 = rb.x, w5 = rb.y, w6 = rb.z, w7 = rb.w;
        rv[0] = __uint_as_float(w0 << 16); rv[8]  = __uint_as_float(w0 & 0xffff0000u);
        rv[1] = __uint_as_float(w1 << 16); rv[9]  = __uint_as_float(w1 & 0xffff0000u);
        rv[2] = __uint_as_float(w2 << 16); rv[10] = __uint_as_float(w2 & 0xffff0000u);
        rv[3] = __uint_as_float(w3 << 16); rv[11] = __uint_as_float(w3 & 0xffff0000u);
        rv[4] = __uint_as_float(w4 << 16); rv[12] = __uint_as_float(w4 & 0xffff0000u);
        rv[5] = __uint_as_float(w5 << 16); rv[13] = __uint_as_float(w5 & 0xffff0000u);
        rv[6] = __uint_as_float(w6 << 16); rv[14] = __uint_as_float(w6 & 0xffff0000u);
        rv[7] = __uint_as_float(w7 << 16); rv[15] = __uint_as_float(w7 & 0xffff0000u);
    } else {
#pragma unroll
        for (int j = 0; j < 16; ++j) rv[j] = 0.0f;
    }

    float acc[16];
#pragma unroll
    for (int j = 0; j < 16; ++j) acc[j] = 0.0f;
    int dsum = 0;

    // ---- prologue: addrtab + loads for tile 0 ----
    u64 rcl[RPT];
    {
        int m0 = total < REC_CAP ? total : REC_CAP;
        if (m0 > 0) {
            for (int r = t; r < nchunks; r += 512) {
                int g_lo = runsum[r], g_hi = runsum[r + 1];
                int lo = g_lo > 0 ? g_lo : 0;
                int hi = g_hi < m0 ? g_hi : m0;
                int a = rbase[r] + (lo - g_lo);
                for (int g = lo; g < hi; ++g, ++a) addrtab[g] = (u32)a;
            }
        }
        __syncthreads();
#pragma unroll
        for (int k = 0; k < RPT; ++k) {
            int i = t + k * 512;
            rcl[k] = (i < m0) ? rec[(size_t)addrtab[i]] : 0;
        }
    }

    for (int tile0 = 0; tile0 < total; tile0 += REC_CAP) {
        int m = total - tile0; if (m > REC_CAP) m = REC_CAP;
        int rnk[RPT];
        // a: count (atomic return = rank)
#pragma unroll
        for (int k = 0; k < RPT; ++k) {
            int i = t + k * 512;
            rnk[k] = (i < m) ? atomicAdd(&hist[(int)(rcl[k] & 0xffu)], 1) : 0;
        }
        __syncthreads();
        // b: scan 256 counts (single wave); base_[BNODES] = m
        if (t < 64) {
            int h0 = hist[4 * t], h1 = hist[4 * t + 1], h2 = hist[4 * t + 2], h3 = hist[4 * t + 3];
            int s4 = h0 + h1 + h2 + h3;
            int inc4 = s4;
#pragma unroll
            for (int d = 1; d < 64; d <<= 1) {
                int x = __shfl_up(inc4, d, 64);
                if (t >= d) inc4 += x;
            }
            int ex = inc4 - s4;
            base_[4 * t] = ex;
            base_[4 * t + 1] = ex + h0;
            base_[4 * t + 2] = ex + h0 + h1;
            base_[4 * t + 3] = ex + h0 + h1 + h2;
            if (t == 63) base_[BNODES] = inc4;   // = m
        }
        __syncthreads();
        // c: scatter + reset hist + fill addrtab for NEXT tile
#pragma unroll
        for (int k = 0; k < RPT; ++k) {
            int i = t + k * 512;
            if (i < m) srec[base_[(int)(rcl[k] & 0xffu)] + rnk[k]] = rcl[k];
        }
        if (t < BNODES) hist[t] = 0;
        int next0 = tile0 + REC_CAP;
        int mn = total - next0; if (mn > REC_CAP) mn = REC_CAP;
        if (mn > 0) {
            for (int r = t; r < nchunks; r += 512) {
                int g_lo = runsum[r], g_hi = runsum[r + 1];
                int lo = g_lo > next0 ? g_lo : next0;
                int hi = g_hi < next0 + mn ? g_hi : next0 + mn;
                int a = rbase[r] + (lo - g_lo);
                for (int g = lo; g < hi; ++g, ++a) addrtab[g - next0] = (u32)a;
            }
        }
        __syncthreads();
        // d: issue next tile's loads, then owner walk (latency hides under it)
        u64 rcln[RPT];
#pragma unroll
        for (int k = 0; k < RPT; ++k) {
            int i = t + k * 512;
            rcln[k] = (mn > 0 && i < mn) ? rec[(size_t)addrtab[i]] : 0;
        }
        {
            int b0_ = nv ? base_[n] : 0;
            int cc  = nv ? (base_[n + 1] - b0_) : 0;
            if (q == 0) dsum += cc;
            for (int k = q; k < cc; k += 2) {
                u64 rc = srec[b0_ + k];
                int l = (int)((rc >> 8) & 0xFFFFFFu);
                float f = __uint_as_float((u32)(rc >> 32));
                const uint4* lp = (const uint4*)(Lpk + (size_t)l * 8);
                uint4 la = lp[0], lb = lp[1];
                u32 w0 = la.x, w1 = la.y, w2 = la.z, w3 = la.w;
                u32 w4 = lb.x, w5 = lb.y, w6 = lb.z, w7 = lb.w;
#define PAIR(h, lw) { \
                float l0 = __uint_as_float(lw << 16); \
                float l1 = __uint_as_float(lw & 0xffff0000u); \
                acc[h]     += fmaxf(fmaf(f, we[h], l0) + rv[h], 0.0f); \
                acc[h + 8] += fmaxf(fmaf(f, we[h + 8], l1) + rv[h + 8], 0.0f); }
                PAIR(0, w0) PAIR(1, w1) PAIR(2, w2) PAIR(3, w3)
                PAIR(4, w4) PAIR(5, w5) PAIR(6, w6) PAIR(7, w7)
#undef PAIR
            }
        }
        __syncthreads();
#pragma unroll
        for (int k = 0; k < RPT; ++k) rcl[k] = rcln[k];
    }

    // combine the 2 owner slices
#pragma unroll
    for (int j = 0; j < 16; ++j) acc[j] += __shfl_xor(acc[j], 1, 64);
    dsum += __shfl_xor(dsum, 1, 64);

    // ---- fused per-node epilogue ----
    if (nv) {
        float rfx[16];
        const float4* Rf = (const float4*)(rf + (size_t)node * EMB);
#pragma unroll
        for (int k = 0; k < 4; ++k) {
            float4 w = Rf[k];
            rfx[4 * k] = w.x; rfx[4 * k + 1] = w.y; rfx[4 * k + 2] = w.z; rfx[4 * k + 3] = w.w;
        }
        float c = (float)dsum;
        float x[16], y[16], z[16], o[16];
#pragma unroll
        for (int j = 0; j < 16; ++j) {
            float a = c * sb[j];
#pragma unroll
            for (int k = 0; k < 16; ++k) a = fmaf(acc[k], sWf[k * 16 + j], a);
            x[j] = fmaxf(a, 0.0f);
        }
#pragma unroll
        for (int j = 0; j < 16; ++j) {
            float a = sb[16 + j];
#pragma unroll
            for (int k = 0; k < 16; ++k) a = fmaf(x[k], sWp[k * 16 + j], a);
            y[j] = a;
        }
#pragma unroll
        for (int j = 0; j < 16; ++j) {
            float a = sb[32 + j];
#pragma unroll
            for (int k = 0; k < 16; ++k) a = fmaf(y[k], sWo1[k * 16 + j], a);
#pragma unroll
            for (int k = 0; k < 16; ++k) a = fmaf(rfx[k], sWo1[(16 + k) * 16 + j], a);
            z[j] = fmaxf(a, 0.0f);
        }
#pragma unroll
        for (int j = 0; j < 16; ++j) {
            float a = sb[48 + j];
#pragma unroll
            for (int k = 0; k < 16; ++k) a = fmaf(z[k], sWo2[k * 16 + j], a);
            o[j] = a;
        }
        float4* Op = (float4*)(out + (size_t)node * EMB);
        Op[q * 2]     = make_float4(o[q * 8],     o[q * 8 + 1], o[q * 8 + 2], o[q * 8 + 3]);
        Op[q * 2 + 1] = make_float4(o[q * 8 + 4], o[q * 8 + 5], o[q * 8 + 6], o[q * 8 + 7]);
    }
}

// ---------------- fallback atomic edge kernel (f32 tables) ----------------
__global__ void edge_kernel(const int* __restrict__ eidx, const float* __restrict__ ef,
                            const float* __restrict__ L, const float* __restrict__ R,
                            const float* __restrict__ We, float* __restrict__ S,
                            int* __restrict__ cnt, int E) {
    long long tid = (long long)blockIdx.x * blockDim.x + threadIdx.x;
    int e = (int)(tid >> 4);
    int j = (int)(tid & 15);
    if (e >= E) return;
    int l = eidx[e];
    int r = eidx[E + e];
    float v = L[(size_t)l * EMB + j] + ef[e] * We[j] + R[(size_t)r * EMB + j];
    v = fmaxf(v, 0.0f);
    unsafeAtomicAdd(&S[(size_t)r * EMB + j], v);
    if (j == 0) atomicAdd(&cnt[r], 1);
}

// ---------------- standalone epilogue (fallback path only) ----------------
__global__ void final_kernel(const float* __restrict__ S, const int* __restrict__ deg,
                             const float* __restrict__ rf,
                             const float* __restrict__ Wf, const float* __restrict__ bf,
                             const float* __restrict__ Wp, const float* __restrict__ bp,
                             const float* __restrict__ Wo1, const float* __restrict__ bo1,
                             const float* __restrict__ Wo2, const float* __restrict__ bo2,
                             float* __restrict__ out, int N) {
    __shared__ float sWf[256], sWp[256], sWo1[512], sWo2[256];
    __shared__ float sb[64];
    int t = threadIdx.x;
    for (int i = t; i < 256; i += 256) { sWf[i] = Wf[i]; sWp[i] = Wp[i]; sWo2[i] = Wo2[i]; }
    for (int i = t; i < 512; i += 256) sWo1[i] = Wo1[i];
    if (t < 16) { sb[t] = bf[t]; sb[16 + t] = bp[t]; sb[32 + t] = bo1[t]; sb[48 + t] = bo2[t]; }
    __syncthreads();

    int r = blockIdx.x * blockDim.x + t;
    if (r >= N) return;

    float s[16], x[16], y[16], rv[16], z[16], o[16];
    const float4* Sp = (const float4*)(S + (size_t)r * EMB);
    const float4* Rp = (const float4*)(rf + (size_t)r * EMB);
#pragma unroll
    for (int k = 0; k < 4; ++k) {
        float4 v = Sp[k];
        s[4 * k] = v.x; s[4 * k + 1] = v.y; s[4 * k + 2] = v.z; s[4 * k + 3] = v.w;
        float4 w = Rp[k];
        rv[4 * k] = w.x; rv[4 * k + 1] = w.y; rv[4 * k + 2] = w.z; rv[4 * k + 3] = w.w;
    }
    float c = (float)deg[r];

#pragma unroll
    for (int j = 0; j < 16; ++j) {
        float a = c * sb[j];
#pragma unroll
        for (int k = 0; k < 16; ++k) a = fmaf(s[k], sWf[k * 16 + j], a);
        x[j] = fmaxf(a, 0.0f);
    }
#pragma unroll
    for (int j = 0; j < 16; ++j) {
        float a = sb[16 + j];
#pragma unroll
        for (int k = 0; k < 16; ++k) a = fmaf(x[k], sWp[k * 16 + j], a);
        y[j] = a;
    }
#pragma unroll
    for (int j = 0; j < 16; ++j) {
        float a = sb[32 + j];
#pragma unroll
        for (int k = 0; k < 16; ++k) a = fmaf(y[k], sWo1[k * 16 + j], a);
#pragma unroll
        for (int k = 0; k < 16; ++k) a = fmaf(rv[k], sWo1[(16 + k) * 16 + j], a);
        z[j] = fmaxf(a, 0.0f);
    }
#pragma unroll
    for (int j = 0; j < 16; ++j) {
        float a = sb[48 + j];
#pragma unroll
        for (int k = 0; k < 16; ++k) a = fmaf(z[k], sWo2[k * 16 + j], a);
        o[j] = a;
    }
    float4* Op = (float4*)(out + (size_t)r * EMB);
#pragma unroll
    for (int k = 0; k < 4; ++k)
        Op[k] = make_float4(o[4 * k], o[4 * k + 1], o[4 * k + 2], o[4 * k + 3]);
}

extern "C" void kernel_launch(void* const* d_in, const int* in_sizes, int n_in,
                              void* d_out, int out_size, void* d_ws, size_t ws_size,
                              hipStream_t stream) {
    const float* lf     = (const float*)d_in[0];
    const int*   eidx   = (const int*)d_in[1];
    const float* ef     = (const float*)d_in[2];
    const float* rf     = (const float*)d_in[3];
    const float* W_left = (const float*)d_in[4];
    const float* b_left = (const float*)d_in[5];
    const float* W_edge = (const float*)d_in[6];
    const float* W_right= (const float*)d_in[7];
    const float* W_final= (const float*)d_in[8];
    const float* b_final= (const float*)d_in[9];
    const float* W_post = (const float*)d_in[10];
    const float* b_post = (const float*)d_in[11];
    const float* W_out1 = (const float*)d_in[12];
    const float* b_out1 = (const float*)d_in[13];
    const float* W_out2 = (const float*)d_in[14];
    const float* b_out2 = (const float*)d_in[15];

    int n_left  = in_sizes[0] / EMB;
    int E       = in_sizes[2];
    int n_right = in_sizes[3] / EMB;
    float* out = (float*)d_out;

    int NB = (n_right + NPB - 1) / NPB;
    int nchunks = (E + PCHUNK - 1) / PCHUNK;

    size_t need = (size_t)E * 8
                + (size_t)NB * nchunks * 8
                + ((size_t)n_left + n_right) * 32;

    if (ws_size >= need && NB <= MAXNB && nchunks <= MAXCHUNKS) {
        u64*  rec = (u64*)d_ws;
        int2* cbM = (int2*)(rec + (size_t)E);
        u32*  Lpk = (u32*)(cbM + (size_t)NB * nchunks);
        u32*  Rpk = Lpk + (size_t)n_left * 8;

        int prows = n_left + n_right;
        pack_both_kernel<<<(prows * 8 + 255) / 256, 256, 0, stream>>>(lf, rf, W_left, b_left, W_right,
                                                                      Lpk, Rpk, n_left, n_right);

        chunk_sort_kernel<<<nchunks, 512, 0, stream>>>(eidx, ef, rec, cbM, E, NB, nchunks);

        bucket_gather_kernel<<<NB, 512, 0, stream>>>(rec, cbM, Lpk, Rpk, W_edge, rf,
                                                     W_final, b_final, W_post, b_post,
                                                     W_out1, b_out1, W_out2, b_out2,
                                                     out, n_right, NB, nchunks);
    } else {
        float* L   = (float*)d_ws;
        float* R   = L + (size_t)n_left * EMB;
        float* S   = R + (size_t)n_right * EMB;
        int*   cnt = (int*)(S + (size_t)n_right * EMB);

        zero_f32<<<2048, 256, 0, stream>>>(S, (size_t)n_right * EMB);
        zero_i32<<<(n_right + 255) / 256, 256, 0, stream>>>(cnt, n_right);

        linear16_kernel<<<(n_left * EMB + 255) / 256, 256, 0, stream>>>(lf, W_left, b_left, L, n_left);
        linear16_kernel<<<(n_right * EMB + 255) / 256, 256, 0, stream>>>(rf, W_right, nullptr, R, n_right);

        long long ethreads = (long long)E * EMB;
        edge_kernel<<<(unsigned)((ethreads + 255) / 256), 256, 0, stream>>>(eidx, ef, L, R, W_edge, S, cnt, E);

        final_kernel<<<(n_right + 255) / 256, 256, 0, stream>>>(S, cnt, rf,
            W_final, b_final, W_post, b_post, W_out1, b_out1, W_out2, b_out2, out, n_right);
    }
}